// Round 2
// baseline (1480.937 us; speedup 1.0000x reference)
//
#include <hip/hip_runtime.h>
#include <math.h>

// SoftRotationSolver: B=64, N=2048
// out R[B,3,3] fp32.  H = dirs_a^T (P/rowsum) dirs_b, then LAPACK-sgesdd-replica
// 3x3 SVD and R = Vh U^T with det-based last-COLUMN flip of Vh.
//
// R = Vh@U^T is NOT SVD-gauge-invariant -> kernel 2 replicates LAPACK
// gesdd small-n path (sgebd2 + sbdsdc->slasdq->sbdsqr) incl. sign conventions.
// R2 FIX: shifted-QR idir=2 rotation targets were swapped. Derivation:
//   first slartg mixes d(i)&e(i-1) (same column) -> ROW rotation -> U
//   second slartg annihilates bulge (i,i-1) vs (i,i) (same row) -> col rot -> VT
// Remaining gauge knobs if needed: (a) pre-3.10 slartg, (b) svd of H^T.

#define NB 64
#define NN 2048
#define EPSW 1e-8f
#define ROWS_PER_BLOCK 128

// ------------------------------------------------------------------ kernel 0
__global__ void k_zero(float* __restrict__ H) {
  int i = blockIdx.x * blockDim.x + threadIdx.x;
  if (i < NB * 9) H[i] = 0.f;
}

// ------------------------------------------------------------------ kernel 1
__global__ __launch_bounds__(256) void k_accum(const float* __restrict__ P,
                                               const float* __restrict__ dirs_a,
                                               const float* __restrict__ dirs_b,
                                               float* __restrict__ Hws) {
  __shared__ __align__(16) float bx[NN];
  __shared__ __align__(16) float by[NN];
  __shared__ __align__(16) float bz[NN];
  const int b = blockIdx.y;
  const int tid = threadIdx.x;

  const float* db = dirs_b + (size_t)b * NN * 3;
  for (int idx = tid; idx < NN * 3; idx += 256) {
    int m = idx / 3;
    int c = idx - 3 * m;
    float v = db[idx];
    if (c == 0) bx[m] = v;
    else if (c == 1) by[m] = v;
    else bz[m] = v;
  }
  __syncthreads();

  const int wave = tid >> 6;
  const int lane = tid & 63;
  const int rbase = blockIdx.x * ROWS_PER_BLOCK;

  float Hacc[9];
#pragma unroll
  for (int i = 0; i < 9; ++i) Hacc[i] = 0.f;

  for (int j = 0; j < 8; ++j) {
    const int n0 = rbase + wave * 32 + j * 4;
    const float4* pr0 = reinterpret_cast<const float4*>(P + ((size_t)b * NN + n0 + 0) * NN);
    const float4* pr1 = reinterpret_cast<const float4*>(P + ((size_t)b * NN + n0 + 1) * NN);
    const float4* pr2 = reinterpret_cast<const float4*>(P + ((size_t)b * NN + n0 + 2) * NN);
    const float4* pr3 = reinterpret_cast<const float4*>(P + ((size_t)b * NN + n0 + 3) * NN);
    float t[4], s0[4], s1[4], s2[4];
#pragma unroll
    for (int r = 0; r < 4; ++r) { t[r] = 0.f; s0[r] = 0.f; s1[r] = 0.f; s2[r] = 0.f; }

#pragma unroll
    for (int it = 0; it < NN / 256; ++it) {
      const int m4 = it * 64 + lane;
      float4 p0 = pr0[m4];
      float4 p1 = pr1[m4];
      float4 p2 = pr2[m4];
      float4 p3 = pr3[m4];
      const int m0 = m4 * 4;
      float4 vx = *reinterpret_cast<const float4*>(&bx[m0]);
      float4 vy = *reinterpret_cast<const float4*>(&by[m0]);
      float4 vz = *reinterpret_cast<const float4*>(&bz[m0]);

      t[0] += (p0.x + p0.y) + (p0.z + p0.w);
      s0[0] += p0.x * vx.x + p0.y * vx.y + p0.z * vx.z + p0.w * vx.w;
      s1[0] += p0.x * vy.x + p0.y * vy.y + p0.z * vy.z + p0.w * vy.w;
      s2[0] += p0.x * vz.x + p0.y * vz.y + p0.z * vz.z + p0.w * vz.w;

      t[1] += (p1.x + p1.y) + (p1.z + p1.w);
      s0[1] += p1.x * vx.x + p1.y * vx.y + p1.z * vx.z + p1.w * vx.w;
      s1[1] += p1.x * vy.x + p1.y * vy.y + p1.z * vy.z + p1.w * vy.w;
      s2[1] += p1.x * vz.x + p1.y * vz.y + p1.z * vz.z + p1.w * vz.w;

      t[2] += (p2.x + p2.y) + (p2.z + p2.w);
      s0[2] += p2.x * vx.x + p2.y * vx.y + p2.z * vx.z + p2.w * vx.w;
      s1[2] += p2.x * vy.x + p2.y * vy.y + p2.z * vy.z + p2.w * vy.w;
      s2[2] += p2.x * vz.x + p2.y * vz.y + p2.z * vz.z + p2.w * vz.w;

      t[3] += (p3.x + p3.y) + (p3.z + p3.w);
      s0[3] += p3.x * vx.x + p3.y * vx.y + p3.z * vx.z + p3.w * vx.w;
      s1[3] += p3.x * vy.x + p3.y * vy.y + p3.z * vy.z + p3.w * vy.w;
      s2[3] += p3.x * vz.x + p3.y * vz.y + p3.z * vz.z + p3.w * vz.w;
    }

#pragma unroll
    for (int r = 0; r < 4; ++r) {
      float tt = t[r], u0 = s0[r], u1 = s1[r], u2 = s2[r];
#pragma unroll
      for (int off = 1; off < 64; off <<= 1) {
        tt += __shfl_xor(tt, off);
        u0 += __shfl_xor(u0, off);
        u1 += __shfl_xor(u1, off);
        u2 += __shfl_xor(u2, off);
      }
      float inv = 1.f / (tt + EPSW);
      float w0 = u0 * inv, w1 = u1 * inv, w2 = u2 * inv;
      const float* dap = dirs_a + ((size_t)b * NN + (n0 + r)) * 3;
      float a0 = dap[0], a1 = dap[1], a2 = dap[2];
      Hacc[0] += a0 * w0; Hacc[1] += a0 * w1; Hacc[2] += a0 * w2;
      Hacc[3] += a1 * w0; Hacc[4] += a1 * w1; Hacc[5] += a1 * w2;
      Hacc[6] += a2 * w0; Hacc[7] += a2 * w1; Hacc[8] += a2 * w2;
    }
  }

  if (lane == 0) {
#pragma unroll
    for (int i = 0; i < 9; ++i) atomicAdd(&Hws[b * 9 + i], Hacc[i]);
  }
}

// ------------------------------------------------------------------ kernel 2
__device__ __forceinline__ float fsign(float a, float b) { return copysignf(a, b); }

__device__ __forceinline__ float slapy2_(float x, float y) {
  float xa = fabsf(x), ya = fabsf(y);
  float w = fmaxf(xa, ya), z = fminf(xa, ya);
  if (z == 0.f) return w;
  float q = z / w;
  return w * sqrtf(1.f + q * q);
}

// LAPACK >=3.10 lartg convention
__device__ float slartg_(float f, float g, float& cs, float& sn) {
  const float safmin = 1.1754943508222875e-38f;
  const float safmax = 3.4028234663852886e+38f;
  float r;
  if (g == 0.f) {
    cs = 1.f; sn = 0.f; r = f;
  } else if (f == 0.f) {
    cs = 0.f; sn = (g > 0.f) ? 1.f : -1.f; r = fabsf(g);
  } else {
    float f1 = fabsf(f), g1 = fabsf(g);
    float rtmin = sqrtf(safmin);
    float rtmax = sqrtf(safmax * 0.5f);
    if (f1 > rtmin && f1 < rtmax && g1 > rtmin && g1 < rtmax) {
      float d = sqrtf(f * f + g * g);
      cs = f1 / d;
      r = copysignf(d, f);
      sn = g / r;
    } else {
      float u = fminf(safmax, fmaxf(safmin, fmaxf(f1, g1)));
      float fs = f / u, gs = g / u;
      float d = sqrtf(fs * fs + gs * gs);
      cs = fabsf(fs) / d;
      r = copysignf(d, f);
      r *= u;
      sn = g / r;
    }
  }
  return r;
}

__device__ void slas2_(float f, float g, float h, float& ssmin, float& ssmax) {
  float fa = fabsf(f), ga = fabsf(g), ha = fabsf(h);
  float fhmn = fminf(fa, ha), fhmx = fmaxf(fa, ha);
  if (fhmn == 0.f) {
    ssmin = 0.f;
    if (fhmx == 0.f) ssmax = ga;
    else {
      float mn = fminf(fhmx, ga), mx = fmaxf(fhmx, ga);
      float q = mn / mx;
      ssmax = mx * sqrtf(1.f + q * q);
    }
  } else {
    if (ga < fhmx) {
      float as_ = 1.f + fhmn / fhmx;
      float at_ = (fhmx - fhmn) / fhmx;
      float au = (ga / fhmx); au = au * au;
      float c = 2.f / (sqrtf(as_ * as_ + au) + sqrtf(at_ * at_ + au));
      ssmin = fhmn * c;
      ssmax = fhmx / c;
    } else {
      float au = fhmx / ga;
      if (au == 0.f) {
        ssmin = (fhmn * fhmx) / ga;
        ssmax = ga;
      } else {
        float as_ = 1.f + fhmn / fhmx;
        float at_ = (fhmx - fhmn) / fhmx;
        float c = 1.f / (sqrtf(1.f + (as_ * au) * (as_ * au)) + sqrtf(1.f + (at_ * au) * (at_ * au)));
        ssmin = (fhmn * c) * au;
        ssmin = ssmin + ssmin;
        ssmax = ga / (c + c);
      }
    }
  }
}

__device__ void slasv2_(float f, float g, float h,
                        float& ssmin, float& ssmax, float& snr, float& csr,
                        float& snl, float& csl) {
  const float eps = 5.9604645e-08f;
  float ft = f, fa = fabsf(f), ht = h, ha = fabsf(h);
  int pmax = 1;
  bool swp = (ha > fa);
  if (swp) {
    pmax = 3;
    float tmp = ft; ft = ht; ht = tmp;
    tmp = fa; fa = ha; ha = tmp;
  }
  float gt = g, ga = fabsf(g);
  float clt = 0.f, crt = 0.f, slt = 0.f, srt = 0.f;
  if (ga == 0.f) {
    ssmin = ha; ssmax = fa;
    clt = 1.f; crt = 1.f; slt = 0.f; srt = 0.f;
  } else {
    bool gasmal = true;
    if (ga > fa) {
      pmax = 2;
      if ((fa / ga) < eps) {
        gasmal = false;
        ssmax = ga;
        if (ha > 1.f) ssmin = fa / (ga / ha);
        else ssmin = (fa / ga) * ha;
        clt = 1.f; slt = ht / gt; srt = 1.f; crt = ft / gt;
      }
    }
    if (gasmal) {
      float dd = fa - ha;
      float l = (dd == fa) ? 1.f : (dd / fa);
      float mq = gt / ft;
      float tq = 2.f - l;
      float mm = mq * mq;
      float tt = tq * tq;
      float sq = sqrtf(tt + mm);
      float rq = (l == 0.f) ? fabsf(mq) : sqrtf(l * l + mm);
      float aq = 0.5f * (sq + rq);
      ssmin = ha / aq;
      ssmax = fa * aq;
      float tv;
      if (mm == 0.f) {
        if (l == 0.f) tv = fsign(2.f, ft) * fsign(1.f, gt);
        else tv = gt / fsign(dd, ft) + mq / tq;
      } else {
        tv = (mq / (sq + tq) + mq / (rq + l)) * (1.f + aq);
      }
      float lv = sqrtf(tv * tv + 4.f);
      crt = 2.f / lv;
      srt = tv / lv;
      clt = (crt + srt * mq) / aq;
      slt = (ht / ft) * srt / aq;
    }
  }
  if (swp) { csl = srt; snl = crt; csr = slt; snr = clt; }
  else     { csl = clt; snl = slt; csr = crt; snr = srt; }
  float tsign = 0.f;
  if (pmax == 1) tsign = fsign(1.f, csr) * fsign(1.f, csl) * fsign(1.f, f);
  if (pmax == 2) tsign = fsign(1.f, snr) * fsign(1.f, csl) * fsign(1.f, g);
  if (pmax == 3) tsign = fsign(1.f, snr) * fsign(1.f, snl) * fsign(1.f, h);
  ssmax = fsign(ssmax, tsign);
  ssmin = fsign(ssmin, tsign * fsign(1.f, f) * fsign(1.f, h));
}

__global__ void k_svd(const float* __restrict__ Hws, float* __restrict__ out) {
  const int b = blockIdx.x;
  if (threadIdx.x != 0) return;

  float A[3][3];
#pragma unroll
  for (int i = 0; i < 3; ++i)
#pragma unroll
    for (int j = 0; j < 3; ++j)
      A[i][j] = Hws[b * 9 + i * 3 + j];

  // ---------- sgebd2 (m=n=3): A = Q B P^T, Q = H1 H2, P = G1 ----------
  float d[4], e[3];
  float tauq1 = 0.f, v11 = 0.f, v12 = 0.f;
  float taup1 = 0.f, w1 = 0.f;
  float tauq2 = 0.f, v2 = 0.f;
  {
    float alpha = A[0][0];
    float xn = sqrtf(A[1][0] * A[1][0] + A[2][0] * A[2][0]);
    if (xn == 0.f) { d[1] = alpha; }
    else {
      float beta = -fsign(slapy2_(alpha, xn), alpha);
      tauq1 = (beta - alpha) / beta;
      float sc = 1.f / (alpha - beta);
      v11 = sc * A[1][0]; v12 = sc * A[2][0];
      d[1] = beta;
    }
    for (int c = 1; c < 3; ++c) {
      float sd = A[0][c] + v11 * A[1][c] + v12 * A[2][c];
      float ts = tauq1 * sd;
      A[0][c] -= ts; A[1][c] -= ts * v11; A[2][c] -= ts * v12;
    }
    alpha = A[0][1];
    xn = fabsf(A[0][2]);
    if (xn == 0.f) { e[1] = alpha; }
    else {
      float beta = -fsign(slapy2_(alpha, xn), alpha);
      taup1 = (beta - alpha) / beta;
      w1 = A[0][2] / (alpha - beta);
      e[1] = beta;
    }
    for (int r = 1; r < 3; ++r) {
      float sd = A[r][1] + w1 * A[r][2];
      float ts = taup1 * sd;
      A[r][1] -= ts; A[r][2] -= ts * w1;
    }
    alpha = A[1][1];
    xn = fabsf(A[2][1]);
    if (xn == 0.f) { d[2] = alpha; }
    else {
      float beta = -fsign(slapy2_(alpha, xn), alpha);
      tauq2 = (beta - alpha) / beta;
      v2 = A[2][1] / (alpha - beta);
      d[2] = beta;
    }
    {
      float sd = A[1][2] + v2 * A[2][2];
      float ts = tauq2 * sd;
      A[1][2] -= ts; A[2][2] -= ts * v2;
    }
    e[2] = A[1][2];
    d[3] = A[2][2];
  }

  float U[3][3]  = {{1.f,0.f,0.f},{0.f,1.f,0.f},{0.f,0.f,1.f}};
  float VT[3][3] = {{1.f,0.f,0.f},{0.f,1.f,0.f},{0.f,0.f,1.f}};

  // ---------- sbdsqr('U', n=3, ncvt=3, nru=3) ----------
  {
    const float eps = 5.9604645e-08f;
    const float unfl = 1.1754943508222875e-38f;
    const float tol = 10.f * eps;
    float sminoa = fabsf(d[1]);
    if (sminoa != 0.f) {
      float mu = sminoa;
      for (int i = 2; i <= 3; ++i) {
        mu = fabsf(d[i]) * (mu / (mu + fabsf(e[i - 1])));
        sminoa = fminf(sminoa, mu);
        if (sminoa == 0.f) break;
      }
    }
    sminoa = sminoa / sqrtf(3.f);
    float thresh = fmaxf(tol * sminoa, 54.f * unfl);

    int m = 3, oldll = -1, oldm = -1, idir = 0;
    float sminl = 0.f;
    int guard = 0;
    while (m > 1 && ++guard < 200) {
      int ll = 0;
      float smaxB = fabsf(d[m]);
      bool split = false;
      for (int lll = 1; lll <= m - 1; ++lll) {
        ll = m - lll;
        float abss = fabsf(d[ll]);
        float abse = fabsf(e[ll]);
        if (abse <= thresh) { split = true; break; }
        smaxB = fmaxf(smaxB, fmaxf(abss, abse));
      }
      if (split) {
        e[ll] = 0.f;
        if (ll == m - 1) { m = m - 1; continue; }
        ll = ll + 1;
      } else {
        ll = 1;
      }
      if (ll == m - 1) {
        float sigmn, sigmx, sinr, cosr, sinl, cosl;
        slasv2_(d[m - 1], e[m - 1], d[m], sigmn, sigmx, sinr, cosr, sinl, cosl);
        d[m - 1] = sigmx; e[m - 1] = 0.f; d[m] = sigmn;
        for (int k = 0; k < 3; ++k) {
          float x = VT[m - 2][k], y = VT[m - 1][k];
          VT[m - 2][k] = cosr * x + sinr * y;
          VT[m - 1][k] = cosr * y - sinr * x;
        }
        for (int k = 0; k < 3; ++k) {
          float x = U[k][m - 2], y = U[k][m - 1];
          U[k][m - 2] = cosl * x + sinl * y;
          U[k][m - 1] = cosl * y - sinl * x;
        }
        m -= 2;
        continue;
      }
      if (ll > oldm || m < oldll)
        idir = (fabsf(d[ll]) >= fabsf(d[m])) ? 1 : 2;

      bool deflated = false;
      if (idir == 1) {
        if (fabsf(e[m - 1]) <= tol * fabsf(d[m])) { e[m - 1] = 0.f; continue; }
        float mu = fabsf(d[ll]); sminl = mu;
        for (int lll = ll; lll <= m - 1; ++lll) {
          if (fabsf(e[lll]) <= tol * mu) { e[lll] = 0.f; deflated = true; break; }
          mu = fabsf(d[lll + 1]) * (mu / (mu + fabsf(e[lll])));
          sminl = fminf(sminl, mu);
        }
      } else {
        if (fabsf(e[ll]) <= tol * fabsf(d[ll])) { e[ll] = 0.f; continue; }
        float mu = fabsf(d[m]); sminl = mu;
        for (int lll = m - 1; lll >= ll; --lll) {
          if (fabsf(e[lll]) <= tol * mu) { e[lll] = 0.f; deflated = true; break; }
          mu = fabsf(d[lll]) * (mu / (mu + fabsf(e[lll])));
          sminl = fminf(sminl, mu);
        }
      }
      if (deflated) continue;
      oldll = ll; oldm = m;

      float shift = 0.f, rdum;
      if (!(3.f * tol * (sminl / smaxB) <= fmaxf(eps, 0.01f * tol))) {
        float sll;
        if (idir == 1) { sll = fabsf(d[ll]); slas2_(d[m - 1], e[m - 1], d[m], shift, rdum); }
        else           { sll = fabsf(d[m]);  slas2_(d[ll], e[ll], d[ll + 1], shift, rdum); }
        if (sll > 0.f) {
          float q = shift / sll;
          if (q * q < eps) shift = 0.f;
        }
      }

      const int nrot = m - ll;
      // cVa/sVa -> applied to VT ; cUa/sUa -> applied to U
      float cVa[2], sVa[2], cUa[2], sUa[2];
      if (shift == 0.f) {
        if (idir == 1) {
          // first lartg: col rotation -> VT ; second: row rotation -> U
          float cs = 1.f, oldcs = 1.f, sn = 0.f, oldsn = 0.f, rr;
          for (int i = ll; i <= m - 1; ++i) {
            rr = slartg_(d[i] * cs, e[i], cs, sn);
            if (i > ll) e[i - 1] = oldsn * rr;
            d[i] = slartg_(oldcs * rr, d[i + 1] * sn, oldcs, oldsn);
            cVa[i - ll] = cs;    sVa[i - ll] = sn;
            cUa[i - ll] = oldcs; sUa[i - ll] = oldsn;
          }
          float h = d[m] * cs;
          d[m] = h * oldcs;
          e[m - 1] = h * oldsn;
          for (int j = 0; j < nrot; ++j) {           // VT rows, forward
            int r1 = ll - 1 + j, r2 = r1 + 1;
            for (int k = 0; k < 3; ++k) {
              float tmp = VT[r2][k];
              VT[r2][k] = cVa[j] * tmp - sVa[j] * VT[r1][k];
              VT[r1][k] = sVa[j] * tmp + cVa[j] * VT[r1][k];
            }
          }
          for (int j = 0; j < nrot; ++j) {           // U cols, forward
            int q1 = ll - 1 + j, q2 = q1 + 1;
            for (int k = 0; k < 3; ++k) {
              float tmp = U[k][q2];
              U[k][q2] = cUa[j] * tmp - sUa[j] * U[k][q1];
              U[k][q1] = sUa[j] * tmp + cUa[j] * U[k][q1];
            }
          }
          if (fabsf(e[m - 1]) <= thresh) e[m - 1] = 0.f;
        } else {
          // bottom-up: first lartg: row rotation -> U ; second -> VT
          float cs = 1.f, oldcs = 1.f, sn = 0.f, oldsn = 0.f, rr;
          for (int i = m; i >= ll + 1; --i) {
            rr = slartg_(d[i] * cs, e[i - 1], cs, sn);
            if (i < m) e[i] = oldsn * rr;
            d[i] = slartg_(oldcs * rr, d[i - 1] * sn, oldcs, oldsn);
            cUa[i - ll - 1] = cs;    sUa[i - ll - 1] = -sn;
            cVa[i - ll - 1] = oldcs; sVa[i - ll - 1] = -oldsn;
          }
          float h = d[ll] * cs;
          d[ll] = h * oldcs;
          e[ll] = h * oldsn;
          for (int j = nrot - 1; j >= 0; --j) {      // VT rows, backward
            int r1 = ll - 1 + j, r2 = r1 + 1;
            for (int k = 0; k < 3; ++k) {
              float tmp = VT[r2][k];
              VT[r2][k] = cVa[j] * tmp - sVa[j] * VT[r1][k];
              VT[r1][k] = sVa[j] * tmp + cVa[j] * VT[r1][k];
            }
          }
          for (int j = nrot - 1; j >= 0; --j) {      // U cols, backward
            int q1 = ll - 1 + j, q2 = q1 + 1;
            for (int k = 0; k < 3; ++k) {
              float tmp = U[k][q2];
              U[k][q2] = cUa[j] * tmp - sUa[j] * U[k][q1];
              U[k][q1] = sUa[j] * tmp + cUa[j] * U[k][q1];
            }
          }
          if (fabsf(e[ll]) <= thresh) e[ll] = 0.f;
        }
      } else {
        if (idir == 1) {
          // first lartg: col rotation -> VT ; second: row rotation -> U
          float f = (fabsf(d[ll]) - shift) * (fsign(1.f, d[ll]) + shift / d[ll]);
          float g = e[ll], cosr, sinr, cosl, sinl, rr;
          for (int i = ll; i <= m - 1; ++i) {
            rr = slartg_(f, g, cosr, sinr);
            if (i > ll) e[i - 1] = rr;
            f = cosr * d[i] + sinr * e[i];
            e[i] = cosr * e[i] - sinr * d[i];
            g = sinr * d[i + 1];
            d[i + 1] = cosr * d[i + 1];
            d[i] = slartg_(f, g, cosl, sinl);
            f = cosl * e[i] + sinl * d[i + 1];
            d[i + 1] = cosl * d[i + 1] - sinl * e[i];
            if (i < m - 1) { g = sinl * e[i + 1]; e[i + 1] = cosl * e[i + 1]; }
            cVa[i - ll] = cosr; sVa[i - ll] = sinr;
            cUa[i - ll] = cosl; sUa[i - ll] = sinl;
          }
          e[m - 1] = f;
          for (int j = 0; j < nrot; ++j) {           // VT rows, forward
            int r1 = ll - 1 + j, r2 = r1 + 1;
            for (int k = 0; k < 3; ++k) {
              float tmp = VT[r2][k];
              VT[r2][k] = cVa[j] * tmp - sVa[j] * VT[r1][k];
              VT[r1][k] = sVa[j] * tmp + cVa[j] * VT[r1][k];
            }
          }
          for (int j = 0; j < nrot; ++j) {           // U cols, forward
            int q1 = ll - 1 + j, q2 = q1 + 1;
            for (int k = 0; k < 3; ++k) {
              float tmp = U[k][q2];
              U[k][q2] = cUa[j] * tmp - sUa[j] * U[k][q1];
              U[k][q1] = sUa[j] * tmp + cUa[j] * U[k][q1];
            }
          }
          if (fabsf(e[m - 1]) <= thresh) e[m - 1] = 0.f;
        } else {
          // R2 FIX: bottom-up shifted sweep.
          // first lartg mixes d(i),e(i-1) (column i) -> ROW rotation -> U
          // second lartg kills bulge (i,i-1) vs (i,i) (row i) -> col rot -> VT
          float f = (fabsf(d[m]) - shift) * (fsign(1.f, d[m]) + shift / d[m]);
          float g = e[m - 1], cosr, sinr, cosl, sinl, rr;
          for (int i = m; i >= ll + 1; --i) {
            rr = slartg_(f, g, cosr, sinr);
            if (i < m) e[i] = rr;
            f = cosr * d[i] + sinr * e[i - 1];
            e[i - 1] = cosr * e[i - 1] - sinr * d[i];
            g = sinr * d[i - 1];
            d[i - 1] = cosr * d[i - 1];
            d[i] = slartg_(f, g, cosl, sinl);
            f = cosl * e[i - 1] + sinl * d[i - 1];
            d[i - 1] = cosl * d[i - 1] - sinl * e[i - 1];
            if (i > ll + 1) { g = sinl * e[i - 2]; e[i - 2] = cosl * e[i - 2]; }
            cUa[i - ll - 1] = cosr; sUa[i - ll - 1] = -sinr;   // was swapped
            cVa[i - ll - 1] = cosl; sVa[i - ll - 1] = -sinl;   // was swapped
          }
          e[ll] = f;
          if (fabsf(e[ll]) <= thresh) e[ll] = 0.f;
          for (int j = nrot - 1; j >= 0; --j) {      // VT rows, backward
            int r1 = ll - 1 + j, r2 = r1 + 1;
            for (int k = 0; k < 3; ++k) {
              float tmp = VT[r2][k];
              VT[r2][k] = cVa[j] * tmp - sVa[j] * VT[r1][k];
              VT[r1][k] = sVa[j] * tmp + cVa[j] * VT[r1][k];
            }
          }
          for (int j = nrot - 1; j >= 0; --j) {      // U cols, backward
            int q1 = ll - 1 + j, q2 = q1 + 1;
            for (int k = 0; k < 3; ++k) {
              float tmp = U[k][q2];
              U[k][q2] = cUa[j] * tmp - sUa[j] * U[k][q1];
              U[k][q1] = sUa[j] * tmp + cUa[j] * U[k][q1];
            }
          }
        }
      }
    }

    // make singular values positive (flip VT rows)
    for (int i = 1; i <= 3; ++i) {
      if (d[i] < 0.f) {
        d[i] = -d[i];
        for (int k = 0; k < 3; ++k) VT[i - 1][k] = -VT[i - 1][k];
      }
    }
    // sort decreasing (LAPACK selection sort)
    for (int i = 1; i <= 2; ++i) {
      int isub = 1;
      float smin = d[1];
      for (int j = 2; j <= 3 + 1 - i; ++j)
        if (d[j] <= smin) { isub = j; smin = d[j]; }
      int tgt = 3 + 1 - i;
      if (isub != tgt) {
        d[isub] = d[tgt]; d[tgt] = smin;
        for (int k = 0; k < 3; ++k) {
          float tmp = VT[isub - 1][k]; VT[isub - 1][k] = VT[tgt - 1][k]; VT[tgt - 1][k] = tmp;
          tmp = U[k][isub - 1]; U[k][isub - 1] = U[k][tgt - 1]; U[k][tgt - 1] = tmp;
        }
      }
    }
  }

  // ---------- back-transform: U = H1 (H2 U_b);  VT = VT_b G1 ----------
  for (int k = 0; k < 3; ++k) {
    float s = U[1][k] + v2 * U[2][k];
    float ts = tauq2 * s;
    U[1][k] -= ts; U[2][k] -= ts * v2;
  }
  for (int k = 0; k < 3; ++k) {
    float s = U[0][k] + v11 * U[1][k] + v12 * U[2][k];
    float ts = tauq1 * s;
    U[0][k] -= ts; U[1][k] -= ts * v11; U[2][k] -= ts * v12;
  }
  for (int r = 0; r < 3; ++r) {
    float s = VT[r][1] + w1 * VT[r][2];
    float ts = taup1 * s;
    VT[r][1] -= ts; VT[r][2] -= ts * w1;
  }

  // ---------- R = VT U^T; det; flip last col of VT; recompute ----------
  float R[3][3];
  for (int i = 0; i < 3; ++i)
    for (int j = 0; j < 3; ++j)
      R[i][j] = VT[i][0] * U[j][0] + VT[i][1] * U[j][1] + VT[i][2] * U[j][2];
  float det = R[0][0] * (R[1][1] * R[2][2] - R[1][2] * R[2][1])
            - R[0][1] * (R[1][0] * R[2][2] - R[1][2] * R[2][0])
            + R[0][2] * (R[1][0] * R[2][1] - R[1][1] * R[2][0]);
  if (det < 0.f) {
    VT[0][2] = -VT[0][2]; VT[1][2] = -VT[1][2]; VT[2][2] = -VT[2][2];
    for (int i = 0; i < 3; ++i)
      for (int j = 0; j < 3; ++j)
        R[i][j] = VT[i][0] * U[j][0] + VT[i][1] * U[j][1] + VT[i][2] * U[j][2];
  }
  for (int i = 0; i < 3; ++i)
    for (int j = 0; j < 3; ++j)
      out[b * 9 + i * 3 + j] = R[i][j];
}

// ------------------------------------------------------------------ launch
extern "C" void kernel_launch(void* const* d_in, const int* in_sizes, int n_in,
                              void* d_out, int out_size, void* d_ws, size_t ws_size,
                              hipStream_t stream) {
  const float* P  = (const float*)d_in[0];
  const float* da = (const float*)d_in[1];
  const float* db = (const float*)d_in[2];
  float* out = (float*)d_out;
  float* Hws = (float*)d_ws;

  hipLaunchKernelGGL(k_zero, dim3(3), dim3(256), 0, stream, Hws);
  hipLaunchKernelGGL(k_accum, dim3(NN / ROWS_PER_BLOCK, NB), dim3(256), 0, stream,
                     P, da, db, Hws);
  hipLaunchKernelGGL(k_svd, dim3(NB), dim3(64), 0, stream, Hws, out);
}